// Round 1
// baseline (727.441 us; speedup 1.0000x reference)
//
#include <hip/hip_runtime.h>

typedef unsigned short u16;
typedef __attribute__((ext_vector_type(4))) unsigned short u16x4;
typedef __attribute__((ext_vector_type(8))) short short8;
typedef __attribute__((ext_vector_type(4))) float f32x4;

#define D_MODEL 1024
#define D_FF    4096
#define NB      16
#define NTOK    1024
#define NEXP    8

// round-to-nearest-even fp32 -> bf16
__device__ __forceinline__ u16 f2bf(float f) {
  union { float f; unsigned u; } v; v.f = f;
  unsigned r = v.u + 0x7FFFu + ((v.u >> 16) & 1u);
  return (u16)(r >> 16);
}

// async global->LDS, 16B per lane; LDS dest is wave-uniform base + lane*16
__device__ __forceinline__ void gld16(const void* g, void* l) {
  __builtin_amdgcn_global_load_lds(
      (const __attribute__((address_space(1))) unsigned int*)g,
      (__attribute__((address_space(3))) unsigned int*)l,
      16, 0, 0);
}

// ---------------------------------------------------------------------------
// x fp32 -> bf16 + per-(b,h) column sums (for router mean) via atomics.
// grid: (64 n-chunks, 16 b), 256 threads; thread covers 4 h, 16 rows.
__global__ void xcvt_kernel(const float* __restrict__ x, u16* __restrict__ xbf,
                            float* __restrict__ sums) {
  const int b = blockIdx.y;
  const int n0 = blockIdx.x * 16;
  const int t = threadIdx.x;
  const int h0 = t * 4;
  const size_t base = ((size_t)b * NTOK + n0) * D_MODEL + h0;
  const float* xp = x + base;
  u16* op = xbf + base;
  float a0 = 0.f, a1 = 0.f, a2 = 0.f, a3 = 0.f;
#pragma unroll
  for (int r = 0; r < 16; ++r) {
    float4 v = *(const float4*)(xp + (size_t)r * D_MODEL);
    a0 += v.x; a1 += v.y; a2 += v.z; a3 += v.w;
    u16x4 o;
    o.x = f2bf(v.x); o.y = f2bf(v.y); o.z = f2bf(v.z); o.w = f2bf(v.w);
    *(u16x4*)(op + (size_t)r * D_MODEL) = o;
  }
  float* s = sums + b * D_MODEL + h0;
  atomicAdd(s + 0, a0); atomicAdd(s + 1, a1);
  atomicAdd(s + 2, a2); atomicAdd(s + 3, a3);
}

// ---------------------------------------------------------------------------
// Router: scores[b][e] = dot(sum_x[b]/N, Wr[:,e]) + br[e]; top-1 argmax per b.
// 1 block, 128 threads = 16 b x 8 e.
__global__ void router_kernel(const float* __restrict__ sums,
                              const float* __restrict__ Wr,
                              const float* __restrict__ br,
                              int* __restrict__ top1, int* __restrict__ used) {
  __shared__ float sc[NB][NEXP];
  const int t = threadIdx.x;
  const int b = t >> 3, e = t & 7;
  if (t < NEXP) used[t] = 0;
  const float* s = sums + b * D_MODEL;
  float acc = 0.f;
  for (int h = 0; h < D_MODEL; ++h) acc += s[h] * Wr[h * NEXP + e];
  sc[b][e] = acc * (1.0f / (float)NTOK) + br[e];
  __syncthreads();
  if (t < NB) {
    float best = sc[t][0]; int bi = 0;
#pragma unroll
    for (int e2 = 1; e2 < NEXP; ++e2) {
      float v = sc[t][e2];
      if (v > best) { best = v; bi = e2; }  // first-max wins, matches argmax
    }
    top1[t] = bi;
    used[bi] = 1;
  }
}

// ---------------------------------------------------------------------------
// Per-expert transpose + fp32->bf16: dst[c][r] = bf16(src[r][c]).
// grid: (C/64, R/64, NEXP), 256 threads, 64x64 tile via padded LDS.
__global__ void wcvt_kernel(const float* __restrict__ src, u16* __restrict__ dst,
                            const int* __restrict__ used, int R, int C) {
  const int e = blockIdx.z;
  if (!used[e]) return;
  __shared__ float tile[64][65];
  const float* s = src + (size_t)e * R * C;
  u16* d = dst + (size_t)e * R * C;
  const int r0 = blockIdx.y * 64, c0 = blockIdx.x * 64;
  const int t = threadIdx.x;
#pragma unroll
  for (int i = 0; i < 16; ++i) {
    int idx = i * 256 + t;
    int r = idx >> 6, c = idx & 63;
    tile[r][c] = s[(size_t)(r0 + r) * C + (c0 + c)];
  }
  __syncthreads();
#pragma unroll
  for (int i = 0; i < 16; ++i) {
    int idx = i * 256 + t;
    int r = idx >> 6, c = idx & 63;
    d[(size_t)(c0 + r) * R + (r0 + c)] = f2bf(tile[c][r]);
  }
}

// ---------------------------------------------------------------------------
// m97-structure bf16 GEMM, B^T form: C[m][n] = sum_k A[m][k] * Bt[n][k].
// 128x128 tile, BK=32, 256 threads (4 waves, 2x2 of 64x64), 4x4 16x16x32 MFMA.
// RELU_BF16=true: out = bf16(relu(acc + bias[col])); else fp32 out = acc+bias.
template <bool RELU_BF16>
__global__ void gemm_bt(const u16* __restrict__ Abase, const u16* __restrict__ Btbase,
                        const float* __restrict__ biasbase, const int* __restrict__ top1,
                        void* __restrict__ OutBase, int K, int Nn) {
  __shared__ __align__(16) u16 As[128 * 32];
  __shared__ __align__(16) u16 Bs[128 * 32];
  const int b = blockIdx.z;
  const int e = top1[b];
  const u16* A = Abase + (size_t)b * NTOK * K;
  const u16* Bt = Btbase + (size_t)e * Nn * K;
  const float* bias = biasbase + (size_t)e * Nn;
  const int tn = blockIdx.x, tm = blockIdx.y;
  const int tid = threadIdx.x;
  const int lane = tid & 63, wave = tid >> 6;
  const int wm = wave & 1, wn = wave >> 1;

  // staging: lane -> (row-in-16-seg, 16B chunk); wave w stages rows
  // [16w,16w+16) and [64+16w, 64+16w+16) of both tiles.
  const int sr = lane >> 2;  // 0..15
  const int sc = lane & 3;   // 0..3
  const u16* gA0 = A + ((size_t)(tm * 128 + wave * 16 + sr)) * K + sc * 8;
  const u16* gB0 = Bt + ((size_t)(tn * 128 + wave * 16 + sr)) * K + sc * 8;
  const size_t half = (size_t)64 * K;
  u16* lA0 = As + wave * (16 * 32);
  u16* lA1 = As + (64 + wave * 16) * 32;
  u16* lB0 = Bs + wave * (16 * 32);
  u16* lB1 = Bs + (64 + wave * 16) * 32;

  // fragment addresses: m/n = lane&15, k-chunk = 8*(lane>>4)
  const int fr = lane & 15, fq = lane >> 4;
  const u16* rA = As + (wm * 64 + fr) * 32 + fq * 8;
  const u16* rB = Bs + (wn * 64 + fr) * 32 + fq * 8;

  f32x4 acc[4][4];
#pragma unroll
  for (int i = 0; i < 4; ++i)
#pragma unroll
    for (int j = 0; j < 4; ++j) acc[i][j] = (f32x4)(0.f);

  for (int k0 = 0; k0 < K; k0 += 32) {
    gld16(gA0 + k0, lA0);
    gld16(gA0 + half + k0, lA1);
    gld16(gB0 + k0, lB0);
    gld16(gB0 + half + k0, lB1);
    __syncthreads();
    short8 afrag[4], bfrag[4];
#pragma unroll
    for (int i = 0; i < 4; ++i) afrag[i] = *(const short8*)(rA + i * (16 * 32));
#pragma unroll
    for (int j = 0; j < 4; ++j) bfrag[j] = *(const short8*)(rB + j * (16 * 32));
#pragma unroll
    for (int i = 0; i < 4; ++i)
#pragma unroll
      for (int j = 0; j < 4; ++j)
        acc[i][j] = __builtin_amdgcn_mfma_f32_16x16x32_bf16(afrag[i], bfrag[j],
                                                            acc[i][j], 0, 0, 0);
    __syncthreads();
  }

  // epilogue: C/D layout col=lane&15, row=4*(lane>>4)+reg
  const int row0 = tm * 128 + wm * 64 + fq * 4;
  const int col0 = tn * 128 + wn * 64 + fr;
  if constexpr (RELU_BF16) {
    u16* Out = (u16*)OutBase + (size_t)b * NTOK * Nn;
#pragma unroll
    for (int i = 0; i < 4; ++i)
#pragma unroll
      for (int j = 0; j < 4; ++j) {
        const int col = col0 + j * 16;
        const float bv = bias[col];
        const int row = row0 + i * 16;
#pragma unroll
        for (int r = 0; r < 4; ++r) {
          float v = acc[i][j][r] + bv;
          v = fmaxf(v, 0.0f);
          Out[(size_t)(row + r) * Nn + col] = f2bf(v);
        }
      }
  } else {
    float* Out = (float*)OutBase + (size_t)b * NTOK * Nn;
#pragma unroll
    for (int i = 0; i < 4; ++i)
#pragma unroll
      for (int j = 0; j < 4; ++j) {
        const int col = col0 + j * 16;
        const float bv = bias[col];
        const int row = row0 + i * 16;
#pragma unroll
        for (int r = 0; r < 4; ++r)
          Out[(size_t)(row + r) * Nn + col] = acc[i][j][r] + bv;
      }
  }
}

// ---------------------------------------------------------------------------
extern "C" void kernel_launch(void* const* d_in, const int* in_sizes, int n_in,
                              void* d_out, int out_size, void* d_ws, size_t ws_size,
                              hipStream_t stream) {
  const float* x  = (const float*)d_in[0];
  const float* Wr = (const float*)d_in[1];
  const float* br = (const float*)d_in[2];
  const float* W1 = (const float*)d_in[3];
  const float* b1 = (const float*)d_in[4];
  const float* W2 = (const float*)d_in[5];
  const float* b2 = (const float*)d_in[6];
  float* out = (float*)d_out;
  char* ws = (char*)d_ws;

  // workspace layout (~304 MB):
  int*   top1 = (int*)(ws + 0);              // 64 B
  int*   used = (int*)(ws + 64);             // 32 B
  float* sums = (float*)(ws + 4096);         // 64 KB
  u16* xbf = (u16*)(ws + (1ull << 20));      // 32 MB  [B][N][H] bf16
  u16* w1t = (u16*)(ws + (48ull << 20));     // 64 MB  [E][F][H] bf16 (W1^T)
  u16* w2t = (u16*)(ws + (112ull << 20));    // 64 MB  [E][H][F] bf16 (W2^T)
  u16* hbf = (u16*)(ws + (176ull << 20));    // 128 MB [B][N][F] bf16

  // zero router accumulators + flags (ws is poisoned 0xAA each launch)
  hipMemsetAsync((void*)ws, 0, 4096 + D_MODEL * NB * sizeof(float), stream);

  xcvt_kernel<<<dim3(NTOK / 16, NB), 256, 0, stream>>>(x, xbf, sums);
  router_kernel<<<1, 128, 0, stream>>>(sums, Wr, br, top1, used);
  // W1 [E][H=1024][F=4096] -> [E][F][H]
  wcvt_kernel<<<dim3(D_FF / 64, D_MODEL / 64, NEXP), 256, 0, stream>>>(
      W1, w1t, used, D_MODEL, D_FF);
  // W2 [E][F=4096][H=1024] -> [E][H][F]
  wcvt_kernel<<<dim3(D_MODEL / 64, D_FF / 64, NEXP), 256, 0, stream>>>(
      W2, w2t, used, D_FF, D_MODEL);
  // GEMM1: h = relu(x @ W1 + b1), M=1024, N=4096, K=1024, bf16 out
  gemm_bt<true><<<dim3(D_FF / 128, NTOK / 128, NB), 256, 0, stream>>>(
      xbf, w1t, b1, top1, (void*)hbf, D_MODEL, D_FF);
  // GEMM2: out = h @ W2 + b2, M=1024, N=1024, K=4096, fp32 out
  gemm_bt<false><<<dim3(D_MODEL / 128, NTOK / 128, NB), 256, 0, stream>>>(
      hbf, w2t, b2, top1, (void*)out, D_FF, D_MODEL);
}